// Round 12
// baseline (54.571 us; speedup 1.0000x reference)
//
#include <hip/hip_runtime.h>

// Chamfer distance via MFMA, B=16, N=M=4096, fp32 in/out. Two dispatches:
//   1) fused main: self-pack targets into LDS -> mfma pair-distance ->
//      row-min -> tile-half combine -> clamp -> block partial sums
//   2) final: 1-block sum of 512 partials -> mean -> out[0]
// d(q,p) = |q|^2 - 2 q.p + |p|^2 inside mfma_f32_32x32x16_bf16 via hi/lo bf16
// splits (k0..k8: Dekker products of (-2q).p; k9,k10: |p|^2; k11,k12: |q|^2).
// R12 = R8's verified inner loop (2 strips/wave, 4 MFMA results in flight)
//       at 8 waves/block (512 thr): waves 0-3 do tiles 0-31 of each chunk,
//       waves 4-7 do tiles 32-63 -> 16 waves/CU (4/SIMD, 2x R8's TLP) at
//       IDENTICAL per-CU pipe loads. Halves combined via R10's verified
//       lmin epilogue.

#define BATCH 16
#define NPTS  4096
#define NQ_TOTAL (BATCH * NPTS)   // 65536 per direction

typedef __attribute__((ext_vector_type(8)))  short bf16x8;
typedef __attribute__((ext_vector_type(16))) float f32x16;
typedef __attribute__((ext_vector_type(4)))  unsigned int u32x4;

union FragCast { bf16x8 v; u32x4 u; };

__device__ __forceinline__ unsigned short bf16_rne(float v) {
    unsigned u = __float_as_uint(v);
    u += 0x7FFFu + ((u >> 16) & 1u);          // round-to-nearest-even
    return (unsigned short)(u >> 16);
}
__device__ __forceinline__ float bf16f(unsigned short h) {
    return __uint_as_float(((unsigned)h) << 16);
}

__global__ __launch_bounds__(512, 4) void chamfer_fused_kernel(
    const float* __restrict__ xyz1, const float* __restrict__ xyz2,
    float* __restrict__ partials)
{
    // 512 blocks; XCD swizzle (512 % 8 == 0, bijective).
    const int orig = (int)blockIdx.x;
    const int wfid = (orig & 7) * 64 + (orig >> 3);
    const int og = wfid & 15;          // strip octet (8 strips)
    const int b  = (wfid >> 4) & 15;   // batch
    const int d  = wfid >> 8;          // direction

    const int tid = (int)threadIdx.x;  // 0..511
    const int wid = tid >> 6;          // 0..7
    const int l   = tid & 63;
    const int lc  = l & 31;            // lane column within 32-half
    const int g   = l >> 5;
    const int wq  = wid & 3;           // strip quad
    const int h   = wid >> 2;          // tile half (0: tiles 0-31, 1: 32-63)
    const int strip0 = og * 8 + wq;    // this wave's two query strips
    const int strip1 = og * 8 + wq + 4;

    const float* qpts = d ? xyz2 : xyz1;   // queries: set d
    const float* tpts = d ? xyz1 : xyz2;   // targets: set 1-d

    // ---- Build the two A-role fragments in registers (R8 encoding) ----
    const unsigned short one = 0x3F80;
    bf16x8 af0, af1;
    #pragma unroll
    for (int s = 0; s < 2; ++s) {
        const int strip = s ? strip1 : strip0;
        const int qi = b * NPTS + strip * 32 + lc;
        const float qx = qpts[qi * 3 + 0];
        const float qy = qpts[qi * 3 + 1];
        const float qz = qpts[qi * 3 + 2];
        const float mx = -2.0f * qx, my = -2.0f * qy, mz = -2.0f * qz;
        const float Q  = fmaf(qx, qx, fmaf(qy, qy, qz * qz));
        const unsigned short xh = bf16_rne(mx), xl = bf16_rne(mx - bf16f(xh));
        const unsigned short yh = bf16_rne(my), yl = bf16_rne(my - bf16f(yh));
        const unsigned short zh = bf16_rne(mz), zl = bf16_rne(mz - bf16f(zh));
        const unsigned short Qh = bf16_rne(Q),  Ql = bf16_rne(Q - bf16f(Qh));
        bf16x8 af;
        if (g == 0) {
            af[0] = (short)xh; af[1] = (short)xh; af[2] = (short)xl; af[3] = (short)yh;
            af[4] = (short)yh; af[5] = (short)yl; af[6] = (short)zh; af[7] = (short)zh;
        } else {
            af[0] = (short)zl; af[1] = (short)one; af[2] = (short)one; af[3] = (short)Qh;
            af[4] = (short)Ql; af[5] = 0;          af[6] = 0;          af[7] = 0;
        }
        if (s) af1 = af; else af0 = af;
    }

    f32x16 vzero;
    #pragma unroll
    for (int i = 0; i < 16; ++i) vzero[i] = 0.0f;

    f32x16 rm0, rm1;
    #pragma unroll
    for (int i = 0; i < 16; ++i) { rm0[i] = 1e30f; rm1[i] = 1e30f; }

    __shared__ u32x4 lds[64 * 64];   // 64 tiles x 64 lanes x 16B = 64 KiB
    __shared__ float lmin[8][64];    // [wave][strip-slot(2) x row(32)]

    const float* tptr = tpts + (size_t)b * NPTS * 3;

    for (int cc = 0; cc < 2; ++cc) {           // 2 chunks x 64 tiles
        __syncthreads();

        // ---- Self-pack chunk cc: 2048 target points, 4 per thread ----
        const float* tb = tptr + (size_t)cc * 2048 * 3;
        #pragma unroll
        for (int k = 0; k < 4; ++k) {
            const int pi = k * 512 + tid;      // 0..2047
            const float x = tb[pi * 3 + 0];
            const float y = tb[pi * 3 + 1];
            const float z = tb[pi * 3 + 2];
            const float S = fmaf(x, x, fmaf(y, y, z * z));
            const unsigned short Xh = bf16_rne(x), Xl = bf16_rne(x - bf16f(Xh));
            const unsigned short Yh = bf16_rne(y), Yl = bf16_rne(y - bf16f(Yh));
            const unsigned short Zh = bf16_rne(z), Zl = bf16_rne(z - bf16f(Zh));
            const unsigned short Sh = bf16_rne(S), Sl = bf16_rne(S - bf16f(Sh));
            FragCast f0, f1;
            f0.v[0] = (short)Xh; f0.v[1] = (short)Xl; f0.v[2] = (short)Xh; f0.v[3] = (short)Yh;
            f0.v[4] = (short)Yl; f0.v[5] = (short)Yh; f0.v[6] = (short)Zh; f0.v[7] = (short)Zl;
            f1.v[0] = (short)Zh; f1.v[1] = (short)Sh; f1.v[2] = (short)Sl; f1.v[3] = (short)one;
            f1.v[4] = (short)one; f1.v[5] = 0;        f1.v[6] = 0;         f1.v[7] = 0;
            const int t  = pi >> 5;
            const int c2 = pi & 31;
            lds[t * 64 + c2]      = f0.u;
            lds[t * 64 + 32 + c2] = f1.u;
        }
        __syncthreads();

        // ---- Inner MFMA loop: this wave's 32-tile half of the chunk ----
        const int t0 = h * 32;
        #pragma unroll 2
        for (int t = t0; t < t0 + 32; t += 2) {
            FragCast ta, tb2;
            ta.u  = lds[(t + 0) * 64 + l];
            tb2.u = lds[(t + 1) * 64 + l];
            f32x16 a0 = __builtin_amdgcn_mfma_f32_32x32x16_bf16(af0, ta.v,  vzero, 0, 0, 0);
            f32x16 a1 = __builtin_amdgcn_mfma_f32_32x32x16_bf16(af0, tb2.v, vzero, 0, 0, 0);
            f32x16 b0 = __builtin_amdgcn_mfma_f32_32x32x16_bf16(af1, ta.v,  vzero, 0, 0, 0);
            f32x16 b1 = __builtin_amdgcn_mfma_f32_32x32x16_bf16(af1, tb2.v, vzero, 0, 0, 0);
            #pragma unroll
            for (int i = 0; i < 16; ++i) {
                rm0[i] = fminf(rm0[i], fminf(a0[i], a1[i]));   // -> v_min3_f32
                rm1[i] = fminf(rm1[i], fminf(b0[i], b1[i]));
            }
        }
    }

    // ---- Cross-lane min over the 32 columns (within each 32-lane half) ----
    #pragma unroll
    for (int m = 1; m <= 16; m <<= 1) {
        #pragma unroll
        for (int i = 0; i < 16; ++i) {
            rm0[i] = fminf(rm0[i], __shfl_xor(rm0[i], m, 64));
            rm1[i] = fminf(rm1[i], __shfl_xor(rm1[i], m, 64));
        }
    }

    // ---- Publish per-row half-mins (rows: (i&3)+8*(i>>2)+4*g) ----
    if (lc == 0) {                      // lanes l=0 (g=0) and l=32 (g=1)
        #pragma unroll
        for (int i = 0; i < 16; ++i) {
            const int row = (i & 3) + 8 * (i >> 2) + 4 * g;
            lmin[wid][0 * 32 + row] = rm0[i];   // strip wq   (slot 0)
            lmin[wid][1 * 32 + row] = rm1[i];   // strip wq+4 (slot 1)
        }
    }
    __syncthreads();

    // ---- Combine tile-halves (waves wq and wq+4), clamp, block sum ----
    // Block-strip s (0..7) row r: halfA = lmin[s&3][(s>>2)*32+r],
    //                             halfB = lmin[(s&3)+4][(s>>2)*32+r].
    float v = 0.0f;
    if (tid < 256) {
        const int s = tid >> 5;
        const int r = tid & 31;
        const int quad = s & 3;
        const int slot = s >> 2;
        v = fmaxf(fminf(lmin[quad][slot * 32 + r], lmin[quad + 4][slot * 32 + r]), 0.0f);
    }

    #pragma unroll
    for (int off = 32; off >= 1; off >>= 1)
        v += __shfl_down(v, off, 64);

    __shared__ float wsum[8];
    if (l == 0) wsum[wid] = v;
    __syncthreads();
    if (tid == 0) {
        float s = 0.0f;
        #pragma unroll
        for (int w = 0; w < 8; ++w) s += wsum[w];
        partials[orig] = s;
    }
}

// ---------------- Pass 2: single-block final sum -> mean -------------------
__global__ __launch_bounds__(256) void final_kernel(
    const float* __restrict__ partials, float* __restrict__ out)
{
    const int t = (int)threadIdx.x;
    float v = partials[t] + partials[t + 256];

    #pragma unroll
    for (int off = 32; off >= 1; off >>= 1)
        v += __shfl_down(v, off, 64);

    __shared__ float wsum[4];
    const int lane = t & 63;
    const int wid  = t >> 6;
    if (lane == 0) wsum[wid] = v;
    __syncthreads();
    if (t == 0)
        out[0] = (wsum[0] + wsum[1] + wsum[2] + wsum[3]) * (1.0f / (float)NQ_TOTAL);
}

extern "C" void kernel_launch(void* const* d_in, const int* in_sizes, int n_in,
                              void* d_out, int out_size, void* d_ws, size_t ws_size,
                              hipStream_t stream) {
    const float* xyz1 = (const float*)d_in[0];
    const float* xyz2 = (const float*)d_in[1];
    float* out = (float*)d_out;
    float* partials = (float*)d_ws;   // 512 floats

    chamfer_fused_kernel<<<512, 512, 0, stream>>>(xyz1, xyz2, partials);
    final_kernel<<<1, 256, 0, stream>>>(partials, out);
}

// Round 13
// 50.840 us; speedup vs baseline: 1.0734x; 1.0734x over previous
//
#include <hip/hip_runtime.h>

// Chamfer distance via MFMA, B=16, N=M=4096, fp32 in/out. Two dispatches:
//   1) fused main: self-pack targets into LDS -> mfma pair-distance ->
//      row-min -> tile-half combine -> clamp -> block partial sums
//   2) final: 1-block sum of 512 partials -> mean -> out[0]
// d(q,p) = |q|^2 - 2 q.p + |p|^2 inside mfma_f32_32x32x16_bf16 via hi/lo bf16
// splits (k0..k8: Dekker products of (-2q).p; k9,k10: |p|^2; k11,k12: |q|^2).
// R13 = R12 (8 waves/block, split tile range, 4 waves/SIMD) with the launch
//       bound relaxed (512,2): R12's (512,4) forced VGPR=64 -> 40MB of scratch
//       spills (FETCH 13MB/WRITE 27MB). ~110 VGPR removes the spill; LDS
//       (68KB -> 2 blocks/CU) still yields 16 waves/CU.

#define BATCH 16
#define NPTS  4096
#define NQ_TOTAL (BATCH * NPTS)   // 65536 per direction

typedef __attribute__((ext_vector_type(8)))  short bf16x8;
typedef __attribute__((ext_vector_type(16))) float f32x16;
typedef __attribute__((ext_vector_type(4)))  unsigned int u32x4;

union FragCast { bf16x8 v; u32x4 u; };

__device__ __forceinline__ unsigned short bf16_rne(float v) {
    unsigned u = __float_as_uint(v);
    u += 0x7FFFu + ((u >> 16) & 1u);          // round-to-nearest-even
    return (unsigned short)(u >> 16);
}
__device__ __forceinline__ float bf16f(unsigned short h) {
    return __uint_as_float(((unsigned)h) << 16);
}

__global__ __launch_bounds__(512, 2) void chamfer_fused_kernel(
    const float* __restrict__ xyz1, const float* __restrict__ xyz2,
    float* __restrict__ partials)
{
    // 512 blocks; XCD swizzle (512 % 8 == 0, bijective).
    const int orig = (int)blockIdx.x;
    const int wfid = (orig & 7) * 64 + (orig >> 3);
    const int og = wfid & 15;          // strip octet (8 strips)
    const int b  = (wfid >> 4) & 15;   // batch
    const int d  = wfid >> 8;          // direction

    const int tid = (int)threadIdx.x;  // 0..511
    const int wid = tid >> 6;          // 0..7
    const int l   = tid & 63;
    const int lc  = l & 31;            // lane column within 32-half
    const int g   = l >> 5;
    const int wq  = wid & 3;           // strip quad
    const int h   = wid >> 2;          // tile half (0: tiles 0-31, 1: 32-63)
    const int strip0 = og * 8 + wq;    // this wave's two query strips
    const int strip1 = og * 8 + wq + 4;

    const float* qpts = d ? xyz2 : xyz1;   // queries: set d
    const float* tpts = d ? xyz1 : xyz2;   // targets: set 1-d

    // ---- Build the two A-role fragments in registers (R8 encoding) ----
    const unsigned short one = 0x3F80;
    bf16x8 af0, af1;
    #pragma unroll
    for (int s = 0; s < 2; ++s) {
        const int strip = s ? strip1 : strip0;
        const int qi = b * NPTS + strip * 32 + lc;
        const float qx = qpts[qi * 3 + 0];
        const float qy = qpts[qi * 3 + 1];
        const float qz = qpts[qi * 3 + 2];
        const float mx = -2.0f * qx, my = -2.0f * qy, mz = -2.0f * qz;
        const float Q  = fmaf(qx, qx, fmaf(qy, qy, qz * qz));
        const unsigned short xh = bf16_rne(mx), xl = bf16_rne(mx - bf16f(xh));
        const unsigned short yh = bf16_rne(my), yl = bf16_rne(my - bf16f(yh));
        const unsigned short zh = bf16_rne(mz), zl = bf16_rne(mz - bf16f(zh));
        const unsigned short Qh = bf16_rne(Q),  Ql = bf16_rne(Q - bf16f(Qh));
        bf16x8 af;
        if (g == 0) {
            af[0] = (short)xh; af[1] = (short)xh; af[2] = (short)xl; af[3] = (short)yh;
            af[4] = (short)yh; af[5] = (short)yl; af[6] = (short)zh; af[7] = (short)zh;
        } else {
            af[0] = (short)zl; af[1] = (short)one; af[2] = (short)one; af[3] = (short)Qh;
            af[4] = (short)Ql; af[5] = 0;          af[6] = 0;          af[7] = 0;
        }
        if (s) af1 = af; else af0 = af;
    }

    f32x16 vzero;
    #pragma unroll
    for (int i = 0; i < 16; ++i) vzero[i] = 0.0f;

    f32x16 rm0, rm1;
    #pragma unroll
    for (int i = 0; i < 16; ++i) { rm0[i] = 1e30f; rm1[i] = 1e30f; }

    __shared__ u32x4 lds[64 * 64];   // 64 tiles x 64 lanes x 16B = 64 KiB
    __shared__ float lmin[8][64];    // [wave][strip-slot(2) x row(32)]

    const float* tptr = tpts + (size_t)b * NPTS * 3;

    for (int cc = 0; cc < 2; ++cc) {           // 2 chunks x 64 tiles
        __syncthreads();

        // ---- Self-pack chunk cc: 2048 target points, 4 per thread ----
        const float* tb = tptr + (size_t)cc * 2048 * 3;
        #pragma unroll
        for (int k = 0; k < 4; ++k) {
            const int pi = k * 512 + tid;      // 0..2047
            const float x = tb[pi * 3 + 0];
            const float y = tb[pi * 3 + 1];
            const float z = tb[pi * 3 + 2];
            const float S = fmaf(x, x, fmaf(y, y, z * z));
            const unsigned short Xh = bf16_rne(x), Xl = bf16_rne(x - bf16f(Xh));
            const unsigned short Yh = bf16_rne(y), Yl = bf16_rne(y - bf16f(Yh));
            const unsigned short Zh = bf16_rne(z), Zl = bf16_rne(z - bf16f(Zh));
            const unsigned short Sh = bf16_rne(S), Sl = bf16_rne(S - bf16f(Sh));
            FragCast f0, f1;
            f0.v[0] = (short)Xh; f0.v[1] = (short)Xl; f0.v[2] = (short)Xh; f0.v[3] = (short)Yh;
            f0.v[4] = (short)Yl; f0.v[5] = (short)Yh; f0.v[6] = (short)Zh; f0.v[7] = (short)Zl;
            f1.v[0] = (short)Zh; f1.v[1] = (short)Sh; f1.v[2] = (short)Sl; f1.v[3] = (short)one;
            f1.v[4] = (short)one; f1.v[5] = 0;        f1.v[6] = 0;         f1.v[7] = 0;
            const int t  = pi >> 5;
            const int c2 = pi & 31;
            lds[t * 64 + c2]      = f0.u;
            lds[t * 64 + 32 + c2] = f1.u;
        }
        __syncthreads();

        // ---- Inner MFMA loop: this wave's 32-tile half of the chunk ----
        const int t0 = h * 32;
        #pragma unroll 2
        for (int t = t0; t < t0 + 32; t += 2) {
            FragCast ta, tb2;
            ta.u  = lds[(t + 0) * 64 + l];
            tb2.u = lds[(t + 1) * 64 + l];
            f32x16 a0 = __builtin_amdgcn_mfma_f32_32x32x16_bf16(af0, ta.v,  vzero, 0, 0, 0);
            f32x16 a1 = __builtin_amdgcn_mfma_f32_32x32x16_bf16(af0, tb2.v, vzero, 0, 0, 0);
            f32x16 b0 = __builtin_amdgcn_mfma_f32_32x32x16_bf16(af1, ta.v,  vzero, 0, 0, 0);
            f32x16 b1 = __builtin_amdgcn_mfma_f32_32x32x16_bf16(af1, tb2.v, vzero, 0, 0, 0);
            #pragma unroll
            for (int i = 0; i < 16; ++i) {
                rm0[i] = fminf(rm0[i], fminf(a0[i], a1[i]));   // -> v_min3_f32
                rm1[i] = fminf(rm1[i], fminf(b0[i], b1[i]));
            }
        }
    }

    // ---- Cross-lane min over the 32 columns (within each 32-lane half) ----
    #pragma unroll
    for (int m = 1; m <= 16; m <<= 1) {
        #pragma unroll
        for (int i = 0; i < 16; ++i) {
            rm0[i] = fminf(rm0[i], __shfl_xor(rm0[i], m, 64));
            rm1[i] = fminf(rm1[i], __shfl_xor(rm1[i], m, 64));
        }
    }

    // ---- Publish per-row half-mins (rows: (i&3)+8*(i>>2)+4*g) ----
    if (lc == 0) {                      // lanes l=0 (g=0) and l=32 (g=1)
        #pragma unroll
        for (int i = 0; i < 16; ++i) {
            const int row = (i & 3) + 8 * (i >> 2) + 4 * g;
            lmin[wid][0 * 32 + row] = rm0[i];   // strip wq   (slot 0)
            lmin[wid][1 * 32 + row] = rm1[i];   // strip wq+4 (slot 1)
        }
    }
    __syncthreads();

    // ---- Combine tile-halves (waves wq and wq+4), clamp, block sum ----
    // Block-strip s (0..7) row r: halfA = lmin[s&3][(s>>2)*32+r],
    //                             halfB = lmin[(s&3)+4][(s>>2)*32+r].
    float v = 0.0f;
    if (tid < 256) {
        const int s = tid >> 5;
        const int r = tid & 31;
        const int quad = s & 3;
        const int slot = s >> 2;
        v = fmaxf(fminf(lmin[quad][slot * 32 + r], lmin[quad + 4][slot * 32 + r]), 0.0f);
    }

    #pragma unroll
    for (int off = 32; off >= 1; off >>= 1)
        v += __shfl_down(v, off, 64);

    __shared__ float wsum[8];
    if (l == 0) wsum[wid] = v;
    __syncthreads();
    if (tid == 0) {
        float s = 0.0f;
        #pragma unroll
        for (int w = 0; w < 8; ++w) s += wsum[w];
        partials[orig] = s;
    }
}

// ---------------- Pass 2: single-block final sum -> mean -------------------
__global__ __launch_bounds__(256) void final_kernel(
    const float* __restrict__ partials, float* __restrict__ out)
{
    const int t = (int)threadIdx.x;
    float v = partials[t] + partials[t + 256];

    #pragma unroll
    for (int off = 32; off >= 1; off >>= 1)
        v += __shfl_down(v, off, 64);

    __shared__ float wsum[4];
    const int lane = t & 63;
    const int wid  = t >> 6;
    if (lane == 0) wsum[wid] = v;
    __syncthreads();
    if (t == 0)
        out[0] = (wsum[0] + wsum[1] + wsum[2] + wsum[3]) * (1.0f / (float)NQ_TOTAL);
}

extern "C" void kernel_launch(void* const* d_in, const int* in_sizes, int n_in,
                              void* d_out, int out_size, void* d_ws, size_t ws_size,
                              hipStream_t stream) {
    const float* xyz1 = (const float*)d_in[0];
    const float* xyz2 = (const float*)d_in[1];
    float* out = (float*)d_out;
    float* partials = (float*)d_ws;   // 512 floats

    chamfer_fused_kernel<<<512, 512, 0, stream>>>(xyz1, xyz2, partials);
    final_kernel<<<1, 256, 0, stream>>>(partials, out);
}

// Round 14
// 47.041 us; speedup vs baseline: 1.1601x; 1.0808x over previous
//
#include <hip/hip_runtime.h>

// Chamfer distance via MFMA, B=16, N=M=4096, fp32 in/out. Three dispatches:
//   1) main: self-pack 32-tile chunks into LDS (32.8KB -> 4 blocks/CU,
//      16 waves/CU) -> R8's verbatim 2-strip/4-in-flight MFMA loop over this
//      block's TILE-HALF -> cross-lane row-min -> write row-mins to ws
//   2) combine: min(half0,half1) -> clamp -> /65536 -> 512 block partials
//   3) final: 1-block sum of 512 partials -> out[0]
// d(q,p) = |q|^2 - 2 q.p + |p|^2 inside mfma_f32_32x32x16_bf16 via hi/lo bf16
// splits (k0..k8: Dekker products of (-2q).p; k9,k10: |p|^2; k11,k12: |q|^2).
// R14 rationale: R8's 256-thr inner loop is the only schedule hipcc compiles
// well (R10/R11/R12/R13 all regressed via VGPR/scheduling); this doubles
// waves/SIMD (2->4) while keeping that code byte-identical.

#define BATCH 16
#define NPTS  4096
#define NQ_TOTAL (BATCH * NPTS)   // 65536 per direction

typedef __attribute__((ext_vector_type(8)))  short bf16x8;
typedef __attribute__((ext_vector_type(16))) float f32x16;
typedef __attribute__((ext_vector_type(4)))  unsigned int u32x4;

union FragCast { bf16x8 v; u32x4 u; };

__device__ __forceinline__ unsigned short bf16_rne(float v) {
    unsigned u = __float_as_uint(v);
    u += 0x7FFFu + ((u >> 16) & 1u);          // round-to-nearest-even
    return (unsigned short)(u >> 16);
}
__device__ __forceinline__ float bf16f(unsigned short h) {
    return __uint_as_float(((unsigned)h) << 16);
}

__global__ __launch_bounds__(256, 2) void chamfer_main_kernel(
    const float* __restrict__ xyz1, const float* __restrict__ xyz2,
    float* __restrict__ rowmin)
{
    // 1024 blocks; XCD swizzle (1024 % 8 == 0, bijective): each XCD slab of
    // 128 consecutive wfid = 4 batches x 16 octets x 2 halves, one direction.
    const int orig = (int)blockIdx.x;
    const int wfid = (orig & 7) * 128 + (orig >> 3);
    const int h  = wfid & 1;           // tile half (0: tiles 0-63, 1: 64-127)
    const int og = (wfid >> 1) & 15;   // strip octet (8 strips)
    const int b  = (wfid >> 5) & 15;   // batch
    const int d  = wfid >> 9;          // direction

    const int tid = (int)threadIdx.x;
    const int wid = tid >> 6;
    const int l   = tid & 63;
    const int lc  = l & 31;            // lane column within 32-half
    const int g   = l >> 5;
    const int strip0 = og * 8 + wid;   // this wave's two query strips
    const int strip1 = og * 8 + wid + 4;

    const float* qpts = d ? xyz2 : xyz1;   // queries: set d
    const float* tpts = d ? xyz1 : xyz2;   // targets: set 1-d

    // ---- Build the two A-role fragments in registers (R8 encoding) ----
    const unsigned short one = 0x3F80;
    bf16x8 af0, af1;
    #pragma unroll
    for (int s = 0; s < 2; ++s) {
        const int strip = s ? strip1 : strip0;
        const int qi = b * NPTS + strip * 32 + lc;
        const float qx = qpts[qi * 3 + 0];
        const float qy = qpts[qi * 3 + 1];
        const float qz = qpts[qi * 3 + 2];
        const float mx = -2.0f * qx, my = -2.0f * qy, mz = -2.0f * qz;
        const float Q  = fmaf(qx, qx, fmaf(qy, qy, qz * qz));
        const unsigned short xh = bf16_rne(mx), xl = bf16_rne(mx - bf16f(xh));
        const unsigned short yh = bf16_rne(my), yl = bf16_rne(my - bf16f(yh));
        const unsigned short zh = bf16_rne(mz), zl = bf16_rne(mz - bf16f(zh));
        const unsigned short Qh = bf16_rne(Q),  Ql = bf16_rne(Q - bf16f(Qh));
        bf16x8 af;
        if (g == 0) {
            af[0] = (short)xh; af[1] = (short)xh; af[2] = (short)xl; af[3] = (short)yh;
            af[4] = (short)yh; af[5] = (short)yl; af[6] = (short)zh; af[7] = (short)zh;
        } else {
            af[0] = (short)zl; af[1] = (short)one; af[2] = (short)one; af[3] = (short)Qh;
            af[4] = (short)Ql; af[5] = 0;          af[6] = 0;          af[7] = 0;
        }
        if (s) af1 = af; else af0 = af;
    }

    f32x16 vzero;
    #pragma unroll
    for (int i = 0; i < 16; ++i) vzero[i] = 0.0f;

    f32x16 rm0, rm1;
    #pragma unroll
    for (int i = 0; i < 16; ++i) { rm0[i] = 1e30f; rm1[i] = 1e30f; }

    __shared__ u32x4 lds[32 * 64];   // 32 tiles x 64 lanes x 16B = 32 KiB

    const float* tptr = tpts + (size_t)b * NPTS * 3;

    for (int cc = 0; cc < 2; ++cc) {           // 2 chunks x 32 tiles (this half)
        __syncthreads();

        // ---- Self-pack chunk: 1024 target points, 4 per thread ----
        const float* tb = tptr + ((size_t)h * 2048 + (size_t)cc * 1024) * 3;
        #pragma unroll
        for (int k = 0; k < 4; ++k) {
            const int pi = k * 256 + tid;      // 0..1023
            const float x = tb[pi * 3 + 0];
            const float y = tb[pi * 3 + 1];
            const float z = tb[pi * 3 + 2];
            const float S = fmaf(x, x, fmaf(y, y, z * z));
            const unsigned short Xh = bf16_rne(x), Xl = bf16_rne(x - bf16f(Xh));
            const unsigned short Yh = bf16_rne(y), Yl = bf16_rne(y - bf16f(Yh));
            const unsigned short Zh = bf16_rne(z), Zl = bf16_rne(z - bf16f(Zh));
            const unsigned short Sh = bf16_rne(S), Sl = bf16_rne(S - bf16f(Sh));
            FragCast f0, f1;
            f0.v[0] = (short)Xh; f0.v[1] = (short)Xl; f0.v[2] = (short)Xh; f0.v[3] = (short)Yh;
            f0.v[4] = (short)Yl; f0.v[5] = (short)Yh; f0.v[6] = (short)Zh; f0.v[7] = (short)Zl;
            f1.v[0] = (short)Zh; f1.v[1] = (short)Sh; f1.v[2] = (short)Sl; f1.v[3] = (short)one;
            f1.v[4] = (short)one; f1.v[5] = 0;        f1.v[6] = 0;         f1.v[7] = 0;
            const int t  = pi >> 5;
            const int c2 = pi & 31;
            lds[t * 64 + c2]      = f0.u;
            lds[t * 64 + 32 + c2] = f1.u;
        }
        __syncthreads();

        // ---- Inner MFMA loop (R8 verbatim): 32 tiles, 2 tiles/iter ----
        #pragma unroll 2
        for (int t = 0; t < 32; t += 2) {
            FragCast ta, tb2;
            ta.u  = lds[(t + 0) * 64 + l];
            tb2.u = lds[(t + 1) * 64 + l];
            f32x16 a0 = __builtin_amdgcn_mfma_f32_32x32x16_bf16(af0, ta.v,  vzero, 0, 0, 0);
            f32x16 a1 = __builtin_amdgcn_mfma_f32_32x32x16_bf16(af0, tb2.v, vzero, 0, 0, 0);
            f32x16 b0 = __builtin_amdgcn_mfma_f32_32x32x16_bf16(af1, ta.v,  vzero, 0, 0, 0);
            f32x16 b1 = __builtin_amdgcn_mfma_f32_32x32x16_bf16(af1, tb2.v, vzero, 0, 0, 0);
            #pragma unroll
            for (int i = 0; i < 16; ++i) {
                rm0[i] = fminf(rm0[i], fminf(a0[i], a1[i]));   // -> v_min3_f32
                rm1[i] = fminf(rm1[i], fminf(b0[i], b1[i]));
            }
        }
    }

    // ---- Cross-lane min over the 32 columns (within each 32-lane half) ----
    #pragma unroll
    for (int m = 1; m <= 16; m <<= 1) {
        #pragma unroll
        for (int i = 0; i < 16; ++i) {
            rm0[i] = fminf(rm0[i], __shfl_xor(rm0[i], m, 64));
            rm1[i] = fminf(rm1[i], __shfl_xor(rm1[i], m, 64));
        }
    }

    // ---- Write this half's row-mins (rows: (i&3)+8*(i>>2)+4*g) ----
    // rowmin[pair][h][slot*32+row], pair = (d*16+b)*16+og, slots: wid, wid+4.
    if (lc == 0) {                      // lanes l=0 (g=0) and l=32 (g=1)
        const size_t base = ((size_t)(((d * 16 + b) * 16 + og) * 2 + h)) * 256;
        #pragma unroll
        for (int i = 0; i < 16; ++i) {
            const int row = (i & 3) + 8 * (i >> 2) + 4 * g;
            rowmin[base + (size_t)wid * 32 + row]       = rm0[i];
            rowmin[base + (size_t)(wid + 4) * 32 + row] = rm1[i];
        }
    }
}

// ---------- Pass 2: combine halves, clamp, mean-scale, block partials ------
__global__ __launch_bounds__(256) void combine_kernel(
    const float* __restrict__ rowmin, float* __restrict__ partials)
{
    const int p = (int)blockIdx.x;     // pair 0..511
    const int j = (int)threadIdx.x;    // query row within pair

    const float a = rowmin[((size_t)p * 2 + 0) * 256 + j];
    const float b = rowmin[((size_t)p * 2 + 1) * 256 + j];
    float v = fmaxf(fminf(a, b), 0.0f) * (1.0f / (float)NQ_TOTAL);

    #pragma unroll
    for (int off = 32; off >= 1; off >>= 1)
        v += __shfl_down(v, off, 64);

    __shared__ float wsum[4];
    const int lane = j & 63;
    const int wid  = j >> 6;
    if (lane == 0) wsum[wid] = v;
    __syncthreads();
    if (j == 0)
        partials[p] = wsum[0] + wsum[1] + wsum[2] + wsum[3];
}

// ---------------- Pass 3: single-block final sum -> out --------------------
__global__ __launch_bounds__(256) void final_kernel(
    const float* __restrict__ partials, float* __restrict__ out)
{
    const int t = (int)threadIdx.x;
    float v = partials[t] + partials[t + 256];

    #pragma unroll
    for (int off = 32; off >= 1; off >>= 1)
        v += __shfl_down(v, off, 64);

    __shared__ float wsum[4];
    const int lane = t & 63;
    const int wid  = t >> 6;
    if (lane == 0) wsum[wid] = v;
    __syncthreads();
    if (t == 0)
        out[0] = wsum[0] + wsum[1] + wsum[2] + wsum[3];
}

extern "C" void kernel_launch(void* const* d_in, const int* in_sizes, int n_in,
                              void* d_out, int out_size, void* d_ws, size_t ws_size,
                              hipStream_t stream) {
    const float* xyz1 = (const float*)d_in[0];
    const float* xyz2 = (const float*)d_in[1];
    float* out = (float*)d_out;

    // ws layout: [0, 1MB) row-mins (512 pairs x 2 halves x 256) | then partials
    float* rowmin   = (float*)d_ws;
    float* partials = (float*)d_ws + 512 * 2 * 256;

    chamfer_main_kernel<<<1024, 256, 0, stream>>>(xyz1, xyz2, rowmin);
    combine_kernel<<<512, 256, 0, stream>>>(rowmin, partials);
    final_kernel<<<1, 256, 0, stream>>>(partials, out);
}

// Round 15
// 42.562 us; speedup vs baseline: 1.2822x; 1.1052x over previous
//
#include <hip/hip_runtime.h>

// Chamfer distance via MFMA, B=16, N=M=4096, fp32 in/out. Two dispatches:
//   1) fused main: self-pack target tiles into LDS -> mfma pair-distance ->
//      row-min -> clamp -> block partial sums
//   2) final: 1-block sum of 512 partials -> mean -> out[0]
// d(q,p) = |q|^2 - 2 q.p + |p|^2 inside mfma_f32_32x32x16_bf16 via hi/lo bf16
// splits (k0..k8: Dekker products of (-2q).p; k9,k10: |p|^2; k11,k12: |q|^2).
// R15 == R8 verbatim (best measured: 27.1 us, absmax 0). R10-R14 established
// that every structural variant (more strips/wave, double-buffer, 512-thr
// blocks, tile-split 2x occupancy) breaks hipcc's 4-MFMA-in-flight schedule
// (VGPR 64-76 compilations, 42-55 us). This exact unit is the local optimum.

#define BATCH 16
#define NPTS  4096
#define NQ_TOTAL (BATCH * NPTS)   // 65536 per direction

typedef __attribute__((ext_vector_type(8)))  short bf16x8;
typedef __attribute__((ext_vector_type(16))) float f32x16;
typedef __attribute__((ext_vector_type(4)))  unsigned int u32x4;

union FragCast { bf16x8 v; u32x4 u; };

__device__ __forceinline__ unsigned short bf16_rne(float v) {
    unsigned u = __float_as_uint(v);
    u += 0x7FFFu + ((u >> 16) & 1u);          // round-to-nearest-even
    return (unsigned short)(u >> 16);
}
__device__ __forceinline__ float bf16f(unsigned short h) {
    return __uint_as_float(((unsigned)h) << 16);
}

__global__ __launch_bounds__(256, 2) void chamfer_fused_kernel(
    const float* __restrict__ xyz1, const float* __restrict__ xyz2,
    float* __restrict__ partials)
{
    // 512 blocks; XCD swizzle (512 % 8 == 0, bijective): each XCD's 64 blocks
    // cover 4 contiguous (b,d) pairs -> their xyz slices live in its L2.
    const int orig = (int)blockIdx.x;
    const int wfid = (orig & 7) * 64 + (orig >> 3);
    const int og = wfid & 15;          // strip octet (8 strips)
    const int b  = (wfid >> 4) & 15;   // batch
    const int d  = wfid >> 8;          // direction

    const int tid = (int)threadIdx.x;
    const int wid = tid >> 6;
    const int l   = tid & 63;
    const int c   = l & 31;
    const int g   = l >> 5;
    const int strip0 = og * 8 + wid;       // this wave's two query strips
    const int strip1 = og * 8 + wid + 4;

    const float* qpts = d ? xyz2 : xyz1;   // queries: set d
    const float* tpts = d ? xyz1 : xyz2;   // targets: set 1-d

    // ---- Build the two A-role fragments in registers ----
    const unsigned short one = 0x3F80;
    bf16x8 af0, af1;
    #pragma unroll
    for (int s = 0; s < 2; ++s) {
        const int strip = s ? strip1 : strip0;
        const int qi = b * NPTS + strip * 32 + c;
        const float qx = qpts[qi * 3 + 0];
        const float qy = qpts[qi * 3 + 1];
        const float qz = qpts[qi * 3 + 2];
        const float mx = -2.0f * qx, my = -2.0f * qy, mz = -2.0f * qz;
        const float Q  = fmaf(qx, qx, fmaf(qy, qy, qz * qz));
        const unsigned short xh = bf16_rne(mx), xl = bf16_rne(mx - bf16f(xh));
        const unsigned short yh = bf16_rne(my), yl = bf16_rne(my - bf16f(yh));
        const unsigned short zh = bf16_rne(mz), zl = bf16_rne(mz - bf16f(zh));
        const unsigned short Qh = bf16_rne(Q),  Ql = bf16_rne(Q - bf16f(Qh));
        bf16x8 af;
        if (g == 0) {
            af[0] = (short)xh; af[1] = (short)xh; af[2] = (short)xl; af[3] = (short)yh;
            af[4] = (short)yh; af[5] = (short)yl; af[6] = (short)zh; af[7] = (short)zh;
        } else {
            af[0] = (short)zl; af[1] = (short)one; af[2] = (short)one; af[3] = (short)Qh;
            af[4] = (short)Ql; af[5] = 0;          af[6] = 0;          af[7] = 0;
        }
        if (s) af1 = af; else af0 = af;
    }

    f32x16 vzero;
    #pragma unroll
    for (int i = 0; i < 16; ++i) vzero[i] = 0.0f;

    f32x16 rm0, rm1;
    #pragma unroll
    for (int i = 0; i < 16; ++i) { rm0[i] = 1e30f; rm1[i] = 1e30f; }

    __shared__ u32x4 lds[64 * 64];   // 64 tiles x 64 lanes x 16B = 64 KiB

    const float* tptr = tpts + (size_t)b * NPTS * 3;

    for (int cc = 0; cc < 2; ++cc) {           // 2 chunks x 64 tiles
        __syncthreads();

        // ---- Self-pack chunk cc: 2048 target points -> B-role fragments ----
        const float* tb = tptr + (size_t)cc * 2048 * 3;
        #pragma unroll
        for (int k = 0; k < 8; ++k) {
            const int pi = k * 256 + tid;      // point within chunk
            const float x = tb[pi * 3 + 0];
            const float y = tb[pi * 3 + 1];
            const float z = tb[pi * 3 + 2];
            const float S = fmaf(x, x, fmaf(y, y, z * z));
            const unsigned short Xh = bf16_rne(x), Xl = bf16_rne(x - bf16f(Xh));
            const unsigned short Yh = bf16_rne(y), Yl = bf16_rne(y - bf16f(Yh));
            const unsigned short Zh = bf16_rne(z), Zl = bf16_rne(z - bf16f(Zh));
            const unsigned short Sh = bf16_rne(S), Sl = bf16_rne(S - bf16f(Sh));
            FragCast f0, f1;
            f0.v[0] = (short)Xh; f0.v[1] = (short)Xl; f0.v[2] = (short)Xh; f0.v[3] = (short)Yh;
            f0.v[4] = (short)Yl; f0.v[5] = (short)Yh; f0.v[6] = (short)Zh; f0.v[7] = (short)Zl;
            f1.v[0] = (short)Zh; f1.v[1] = (short)Sh; f1.v[2] = (short)Sl; f1.v[3] = (short)one;
            f1.v[4] = (short)one; f1.v[5] = 0;        f1.v[6] = 0;         f1.v[7] = 0;
            const int t  = pi >> 5;
            const int c2 = pi & 31;
            lds[t * 64 + c2]      = f0.u;   // g=0 chunk for point c2
            lds[t * 64 + 32 + c2] = f1.u;   // g=1 chunk
        }
        __syncthreads();

        // ---- Inner MFMA loop ----
        #pragma unroll 2
        for (int t = 0; t < 64; t += 2) {
            FragCast ta, tb2;
            ta.u  = lds[(t + 0) * 64 + l];
            tb2.u = lds[(t + 1) * 64 + l];
            // 1 ds_read pair feeds 4 MFMAs (2 strips x 2 tiles)
            f32x16 a0 = __builtin_amdgcn_mfma_f32_32x32x16_bf16(af0, ta.v,  vzero, 0, 0, 0);
            f32x16 a1 = __builtin_amdgcn_mfma_f32_32x32x16_bf16(af0, tb2.v, vzero, 0, 0, 0);
            f32x16 b0 = __builtin_amdgcn_mfma_f32_32x32x16_bf16(af1, ta.v,  vzero, 0, 0, 0);
            f32x16 b1 = __builtin_amdgcn_mfma_f32_32x32x16_bf16(af1, tb2.v, vzero, 0, 0, 0);
            #pragma unroll
            for (int i = 0; i < 16; ++i) {
                rm0[i] = fminf(rm0[i], fminf(a0[i], a1[i]));   // -> v_min3_f32
                rm1[i] = fminf(rm1[i], fminf(b0[i], b1[i]));
            }
        }
    }

    // Cross-lane min over the 32 columns (within each 32-lane half; halves
    // hold disjoint row sets per C layout row=(i&3)+8*(i>>2)+4*g).
    #pragma unroll
    for (int m = 1; m <= 16; m <<= 1) {
        #pragma unroll
        for (int i = 0; i < 16; ++i) {
            rm0[i] = fminf(rm0[i], __shfl_xor(rm0[i], m, 64));
            rm1[i] = fminf(rm1[i], __shfl_xor(rm1[i], m, 64));
        }
    }

    // Clamp (min of clamped == clamp of min) and sum this wave's 64 rows.
    float s0 = 0.0f, s1 = 0.0f;
    #pragma unroll
    for (int i = 0; i < 16; ++i) {
        s0 += fmaxf(rm0[i], 0.0f);
        s1 += fmaxf(rm1[i], 0.0f);
    }
    s0 += __shfl_xor(s0, 32, 64);
    s1 += __shfl_xor(s1, 32, 64);
    const float s = s0 + s1;

    __shared__ float wsum[4];
    if (l == 0) wsum[wid] = s;
    __syncthreads();
    if (tid == 0)
        partials[orig] = wsum[0] + wsum[1] + wsum[2] + wsum[3];
}

// ---------------- Pass 2: single-block final sum -> mean -------------------
__global__ __launch_bounds__(256) void final_kernel(
    const float* __restrict__ partials, float* __restrict__ out)
{
    const int t = (int)threadIdx.x;
    float v = partials[t] + partials[t + 256];

    #pragma unroll
    for (int off = 32; off >= 1; off >>= 1)
        v += __shfl_down(v, off, 64);

    __shared__ float wsum[4];
    const int lane = t & 63;
    const int wid  = t >> 6;
    if (lane == 0) wsum[wid] = v;
    __syncthreads();
    if (t == 0)
        out[0] = (wsum[0] + wsum[1] + wsum[2] + wsum[3]) * (1.0f / (float)NQ_TOTAL);
}

extern "C" void kernel_launch(void* const* d_in, const int* in_sizes, int n_in,
                              void* d_out, int out_size, void* d_ws, size_t ws_size,
                              hipStream_t stream) {
    const float* xyz1 = (const float*)d_in[0];
    const float* xyz2 = (const float*)d_in[1];
    float* out = (float*)d_out;
    float* partials = (float*)d_ws;   // 512 floats

    chamfer_fused_kernel<<<512, 256, 0, stream>>>(xyz1, xyz2, partials);
    final_kernel<<<1, 256, 0, stream>>>(partials, out);
}

// Round 16
// 42.218 us; speedup vs baseline: 1.2926x; 1.0081x over previous
//
#include <hip/hip_runtime.h>

// Chamfer distance via MFMA, B=16, N=M=4096, fp32 in/out. Two dispatches:
//   1) fused main: self-pack target tiles into LDS -> mfma pair-distance ->
//      row-min -> clamp -> block partial sums
//   2) final: 1-block sum of 512 partials -> mean -> out[0]
// d(q,p) = |q|^2 - 2 q.p + |p|^2 inside mfma_f32_32x32x16_bf16 via hi/lo bf16
// splits (k0..k8: Dekker products of (-2q).p; k9,k10: |p|^2; k11,k12: |q|^2).

#define BATCH 16
#define NPTS  4096
#define NQ_TOTAL (BATCH * NPTS)   // 65536 per direction

typedef __attribute__((ext_vector_type(8)))  short bf16x8;
typedef __attribute__((ext_vector_type(16))) float f32x16;
typedef __attribute__((ext_vector_type(4)))  unsigned int u32x4;

union FragCast { bf16x8 v; u32x4 u; };

__device__ __forceinline__ unsigned short bf16_rne(float v) {
    unsigned u = __float_as_uint(v);
    u += 0x7FFFu + ((u >> 16) & 1u);          // round-to-nearest-even
    return (unsigned short)(u >> 16);
}
__device__ __forceinline__ float bf16f(unsigned short h) {
    return __uint_as_float(((unsigned)h) << 16);
}

__global__ __launch_bounds__(256, 2) void chamfer_fused_kernel(
    const float* __restrict__ xyz1, const float* __restrict__ xyz2,
    float* __restrict__ partials)
{
    // 512 blocks; XCD swizzle (512 % 8 == 0, bijective): each XCD's 64 blocks
    // cover 4 contiguous (b,d) pairs -> their xyz slices live in its L2.
    const int orig = (int)blockIdx.x;
    const int wfid = (orig & 7) * 64 + (orig >> 3);
    const int og = wfid & 15;          // strip octet (8 strips)
    const int b  = (wfid >> 4) & 15;   // batch
    const int d  = wfid >> 8;          // direction

    const int tid = (int)threadIdx.x;
    const int wid = tid >> 6;
    const int l   = tid & 63;
    const int c   = l & 31;
    const int g   = l >> 5;
    const int strip0 = og * 8 + wid;       // this wave's two query strips
    const int strip1 = og * 8 + wid + 4;

    const float* qpts = d ? xyz2 : xyz1;   // queries: set d
    const float* tpts = d ? xyz1 : xyz2;   // targets: set 1-d

    // ---- Build the two A-role fragments in registers (same as R6) ----
    const unsigned short one = 0x3F80;
    bf16x8 af0, af1;
    #pragma unroll
    for (int s = 0; s < 2; ++s) {
        const int strip = s ? strip1 : strip0;
        const int qi = b * NPTS + strip * 32 + c;
        const float qx = qpts[qi * 3 + 0];
        const float qy = qpts[qi * 3 + 1];
        const float qz = qpts[qi * 3 + 2];
        const float mx = -2.0f * qx, my = -2.0f * qy, mz = -2.0f * qz;
        const float Q  = fmaf(qx, qx, fmaf(qy, qy, qz * qz));
        const unsigned short xh = bf16_rne(mx), xl = bf16_rne(mx - bf16f(xh));
        const unsigned short yh = bf16_rne(my), yl = bf16_rne(my - bf16f(yh));
        const unsigned short zh = bf16_rne(mz), zl = bf16_rne(mz - bf16f(zh));
        const unsigned short Qh = bf16_rne(Q),  Ql = bf16_rne(Q - bf16f(Qh));
        bf16x8 af;
        if (g == 0) {
            af[0] = (short)xh; af[1] = (short)xh; af[2] = (short)xl; af[3] = (short)yh;
            af[4] = (short)yh; af[5] = (short)yl; af[6] = (short)zh; af[7] = (short)zh;
        } else {
            af[0] = (short)zl; af[1] = (short)one; af[2] = (short)one; af[3] = (short)Qh;
            af[4] = (short)Ql; af[5] = 0;          af[6] = 0;          af[7] = 0;
        }
        if (s) af1 = af; else af0 = af;
    }

    f32x16 vzero;
    #pragma unroll
    for (int i = 0; i < 16; ++i) vzero[i] = 0.0f;

    f32x16 rm0, rm1;
    #pragma unroll
    for (int i = 0; i < 16; ++i) { rm0[i] = 1e30f; rm1[i] = 1e30f; }

    __shared__ u32x4 lds[64 * 64];   // 64 tiles x 64 lanes x 16B = 64 KiB

    for (int cc = 0; cc < 2; ++cc) {           // 2 chunks x 64 tiles
        __syncthreads();

        // ---- Self-pack chunk cc: 2048 target points -> B-role fragments ----
        const float* tb = tpts + ((size_t)b * NPTS + (size_t)cc * 2048) * 3;
        #pragma unroll
        for (int k = 0; k < 8; ++k) {
            const int pi = k * 256 + tid;      // point within chunk
            const float x = tb[pi * 3 + 0];
            const float y = tb[pi * 3 + 1];
            const float z = tb[pi * 3 + 2];
            const float S = fmaf(x, x, fmaf(y, y, z * z));
            const unsigned short Xh = bf16_rne(x), Xl = bf16_rne(x - bf16f(Xh));
            const unsigned short Yh = bf16_rne(y), Yl = bf16_rne(y - bf16f(Yh));
            const unsigned short Zh = bf16_rne(z), Zl = bf16_rne(z - bf16f(Zh));
            const unsigned short Sh = bf16_rne(S), Sl = bf16_rne(S - bf16f(Sh));
            FragCast f0, f1;
            f0.v[0] = (short)Xh; f0.v[1] = (short)Xl; f0.v[2] = (short)Xh; f0.v[3] = (short)Yh;
            f0.v[4] = (short)Yl; f0.v[5] = (short)Yh; f0.v[6] = (short)Zh; f0.v[7] = (short)Zl;
            f1.v[0] = (short)Zh; f1.v[1] = (short)Sh; f1.v[2] = (short)Sl; f1.v[3] = (short)one;
            f1.v[4] = (short)one; f1.v[5] = 0;        f1.v[6] = 0;         f1.v[7] = 0;
            const int t  = pi >> 5;
            const int c2 = pi & 31;
            lds[t * 64 + c2]      = f0.u;   // g=0 chunk for point c2
            lds[t * 64 + 32 + c2] = f1.u;   // g=1 chunk
        }
        __syncthreads();

        // ---- Inner MFMA loop (identical op order to R6) ----
        #pragma unroll 2
        for (int t = 0; t < 64; t += 2) {
            FragCast ta, tb2;
            ta.u  = lds[(t + 0) * 64 + l];
            tb2.u = lds[(t + 1) * 64 + l];
            // 1 ds_read pair feeds 4 MFMAs (2 strips x 2 tiles)
            f32x16 a0 = __builtin_amdgcn_mfma_f32_32x32x16_bf16(af0, ta.v,  vzero, 0, 0, 0);
            f32x16 a1 = __builtin_amdgcn_mfma_f32_32x32x16_bf16(af0, tb2.v, vzero, 0, 0, 0);
            f32x16 b0 = __builtin_amdgcn_mfma_f32_32x32x16_bf16(af1, ta.v,  vzero, 0, 0, 0);
            f32x16 b1 = __builtin_amdgcn_mfma_f32_32x32x16_bf16(af1, tb2.v, vzero, 0, 0, 0);
            #pragma unroll
            for (int i = 0; i < 16; ++i) {
                rm0[i] = fminf(rm0[i], fminf(a0[i], a1[i]));   // -> v_min3_f32
                rm1[i] = fminf(rm1[i], fminf(b0[i], b1[i]));
            }
        }
    }

    // Cross-lane min over the 32 columns (within each 32-lane half; halves
    // hold disjoint row sets per C layout row=(i&3)+8*(i>>2)+4*g).
    #pragma unroll
    for (int m = 1; m <= 16; m <<= 1) {
        #pragma unroll
        for (int i = 0; i < 16; ++i) {
            rm0[i] = fminf(rm0[i], __shfl_xor(rm0[i], m, 64));
            rm1[i] = fminf(rm1[i], __shfl_xor(rm1[i], m, 64));
        }
    }

    // Clamp (min of clamped == clamp of min) and sum this wave's 64 rows.
    float s0 = 0.0f, s1 = 0.0f;
    #pragma unroll
    for (int i = 0; i < 16; ++i) {
        s0 += fmaxf(rm0[i], 0.0f);
        s1 += fmaxf(rm1[i], 0.0f);
    }
    s0 += __shfl_xor(s0, 32, 64);
    s1 += __shfl_xor(s1, 32, 64);
    const float s = s0 + s1;

    __shared__ float wsum[4];
    if (l == 0) wsum[wid] = s;
    __syncthreads();
    if (tid == 0)
        partials[orig] = wsum[0] + wsum[1] + wsum[2] + wsum[3];
}

// ---------------- Pass 2: single-block final sum -> mean -------------------
__global__ __launch_bounds__(256) void final_kernel(
    const float* __restrict__ partials, float* __restrict__ out)
{
    const int t = (int)threadIdx.x;
    float v = partials[t] + partials[t + 256];

    #pragma unroll
    for (int off = 32; off >= 1; off >>= 1)
        v += __shfl_down(v, off, 64);

    __shared__ float wsum[4];
    const int lane = t & 63;
    const int wid  = t >> 6;
    if (lane == 0) wsum[wid] = v;
    __syncthreads();
    if (t == 0)
        out[0] = (wsum[0] + wsum[1] + wsum[2] + wsum[3]) * (1.0f / (float)NQ_TOTAL);
}

extern "C" void kernel_launch(void* const* d_in, const int* in_sizes, int n_in,
                              void* d_out, int out_size, void* d_ws, size_t ws_size,
                              hipStream_t stream) {
    const float* xyz1 = (const float*)d_in[0];
    const float* xyz2 = (const float*)d_in[1];
    float* out = (float*)d_out;
    float* partials = (float*)d_ws;   // 512 floats

    chamfer_fused_kernel<<<512, 256, 0, stream>>>(xyz1, xyz2, partials);
    final_kernel<<<1, 256, 0, stream>>>(partials, out);
}